// Round 4
// baseline (164.263 us; speedup 1.0000x reference)
//
#include <hip/hip_runtime.h>
#include <math.h>

#define IMG_W 3840
#define IMG_H 2160
#define OUTW  60        // output columns per wave strip (64 lanes - 4 halo)
#define R     12        // output rows per strip (2160 = 180 * 12, exact)
#define GROWS (R + 4)   // 16 gray rows per strip

// idx -> dx [1,1,0,-1,-1,-1,0,1], dy [0,1,1,1,0,-1,-1,-1], packed as (d+1) 2-bit fields
#define DXPACK 0x901A
#define DYPACK 0x1A9

// Sector boundary slopes in the module's scaled-degree space (RAD2DEG = 180/3.14159)
#define T1_SLOPE 0.41421317376456f
#define T2_SLOPE 2.41420676743300f
#define SECT_EPS 3.0e-5f

__device__ __noinline__ int slow_sector(float sx, float sy) {
#pragma clang fp contract(off)
    const float RADF = (float)(180.0 / 3.14159);
    float t = atan2f(sy, sx);
    float wv = ((t * RADF) + 180.0f) / 45.0f;   // exact f32 chain as reference
    float ori = rintf(wv);                      // round-half-even == np.round
    float fr = fabsf(wv - ori);
    if (fr > 0.4995f) {
        // near a rounding tie: redo atan2 in double -> correctly-rounded f32
        double td = atan2((double)sy, (double)sx);
        float t2 = (float)td;
        wv = ((t2 * RADF) + 180.0f) / 45.0f;
        ori = rintf(wv);
    }
    return ((int)ori) & 7;
}

// ---- all array indices are literal constants (rule #20: no runtime-indexed
//      register arrays). Straight-line schedule, quad-row basic blocks. ----

// issue 3 channel loads of gray row (kk) into 8-slot buffer slot cj = kk&7
#define LOADROW(kk, cj)                                                        \
    {                                                                          \
        const int y_  = Y0 - 2 + (kk);                                         \
        const int yc_ = min(max(y_, 0), IMG_H - 1);                            \
        const int o_  = yc_ * IMG_W + xc;                                      \
        c0[(cj)] = img[o_];                                                    \
        c1[(cj)] = im1[o_];                                                    \
        c2[(cj)] = im2[o_];                                                    \
    }

// consume c-slot cj (= kk&7): gray value + neighbor shuffles into window slot j7 (= kk&7)
#define GRAY8(kk, cj, j7)                                                      \
    {                                                                          \
        const int  y_   = Y0 - 2 + (kk);                                       \
        const bool yok_ = (unsigned)y_ < (unsigned)IMG_H;                      \
        float t_  = ((c0[(cj)] + c1[(cj)]) + c2[(cj)]) / 3.0f;                 \
        float gv_ = (xok && yok_) ? t_ : 0.0f;                                 \
        g[(j7)]  = gv_;                                                        \
        gl[(j7)] = __shfl_up(gv_, 1);                                          \
        gr[(j7)] = __shfl_down(gv_, 1);                                       \
    }

// Sobel + fast sector for mag row kk (image row Y0-3+kk) from gray kk-2,kk-1,kk.
// Outputs: MG (masked mag), OF (masked NMS offset), SX/SY (for rare fix), CC (eps cond).
// Writes mag into LDS ring slot kk&7.
#define SOBEL(kk, MG, OF, SX, SY, CC)                                          \
    {                                                                          \
        const int i0_ = ((kk) + 6) & 7, i1_ = ((kk) + 7) & 7, i2_ = (kk) & 7;  \
        float a00 = gl[i0_], a01 = g[i0_], a02 = gr[i0_];                      \
        float a10 = gl[i1_],               a12 = gr[i1_];                      \
        float a20 = gl[i2_], a21 = g[i2_], a22 = gr[i2_];                      \
        float sx = a00;                      /* exact R4 tap order */          \
        sx = sx - a02;                                                         \
        sx = sx + 2.0f * a10;                                                  \
        sx = sx - 2.0f * a12;                                                  \
        sx = sx + a20;                                                         \
        sx = sx - a22;                                                         \
        float sy = a00;                                                        \
        sy = sy + 2.0f * a01;                                                  \
        sy = sy + a02;                                                         \
        sy = sy - a20;                                                         \
        sy = sy - 2.0f * a21;                                                  \
        sy = sy - a22;                                                         \
        float magv = sqrtf(sx * sx + sy * sy);                                 \
        float ax = fabsf(sx), ay = fabsf(sy);                                  \
        float d1 = fmaf(-T1_SLOPE, ax, ay);                                    \
        float d2 = fmaf(-T2_SLOPE, ax, ay);                                    \
        float sA = ax + ay;                                                    \
        (SX) = sx; (SY) = sy;                                                  \
        (CC) = (fabsf(d1) < SECT_EPS * sA) || (fabsf(d2) < SECT_EPS * sA);     \
        int dxo = (d2 > 0.0f) ? 0 : ((sx > 0.0f) ? -1 : 1);                    \
        int dyo = (d1 < 0.0f) ? 0 : ((sy > 0.0f) ? -1 : 1);                    \
        const bool vok_ = xmok && ((unsigned)(Y0 - 3 + (kk)) < (unsigned)IMG_H); \
        (MG) = vok_ ? magv : 0.0f;                                             \
        (OF) = vok_ ? (dyo * 64 + dxo) : 0;                                    \
        B[((kk) & 7) * 64 + lane] = (MG);    /* ring slot kk&7 */              \
    }

// rare exact-path fix-up (inside the once-per-quad outer branch)
#define FIXROW(kk, OF, SX, SY, CC)                                             \
    if (CC) {                                                                  \
        int idx_ = slow_sector((SX), (SY));                                    \
        int dxo_ = ((DXPACK >> (2 * idx_)) & 3) - 1;                           \
        int dyo_ = ((DYPACK >> (2 * idx_)) & 3) - 1;                           \
        const bool vok_ = xmok && ((unsigned)(Y0 - 3 + (kk)) < (unsigned)IMG_H); \
        (OF) = vok_ ? (dyo_ * 64 + dxo_) : 0;                                  \
    }

// NMS for center mag row M (out image row Y0+M-3): reads ring slots M-1,M,M+1.
// Same-wave DS ops are in-order -> no barrier. &511 wrap: (slot*64 + dy*64 +
// lane + dx) & 511 == ((M+dy)&7)*64 + (lane+dx) whenever 0 <= lane+dx <= 63
// (true for all lanes whose result is stored: xoutok lanes 2..61).
#define NMSROW(M, MC, OFC)                                                     \
    {                                                                          \
        const int rp_  = ((M) & 7) * 64;                                       \
        const int ipp_ = (rp_ + lane + (OFC)) & 511;                           \
        const int ipn_ = (rp_ + lane - (OFC)) & 511;                           \
        float mp_ = B[ipp_];                                                   \
        float mn_ = B[ipn_];                                                   \
        float res_ = (fminf((MC) - mp_, (MC) - mn_) > 0.0f &&                  \
                      (MC) >= 0.2f) ? 1.0f : 0.0f;                             \
        if (xoutok)                                                            \
            out[(size_t)(Y0 + (M) - 3) * IMG_W + x] = res_;                    \
    }

__global__ __launch_bounds__(256, 4) void canny_like_kernel(const float* __restrict__ img,
                                                            float* __restrict__ out) {
#pragma clang fp contract(off)
    // per-wave 8-row circular mag ring: 8 KB/block, no barriers anywhere
    __shared__ float lds_m[4][8][64];

    const int lane = threadIdx.x;                // 0..63
    const int w    = threadIdx.y;                // wave id in block, 0..3
    const int X0   = (blockIdx.x * 4 + w) * OUTW;
    const int Y0   = blockIdx.y * R;
    const int x    = X0 - 2 + lane;              // gray column owned by this lane
    const bool xok    = (unsigned)x < (unsigned)IMG_W;
    const int  xc     = min(max(x, 0), IMG_W - 1);       // clamped (safe addr, value masked)
    const bool xmok   = (lane >= 1) && (lane <= 62) && xok;   // mag-valid lanes
    const bool xoutok = (lane >= 2) && (lane <= 61);          // output lanes

    const float* im1 = img + (size_t)IMG_W * IMG_H;
    const float* im2 = img + 2 * (size_t)IMG_W * IMG_H;

    float* const B = &lds_m[w][0][0];            // wave-private 512-float ring

    // pipeline state: 8-slot channel buffers (24 loads in flight) + 8-slot
    // rolling gray window. Indices ALWAYS literal -> registers, never scratch.
    float c0[8], c1[8], c2[8];
    float g[8], gl[8], gr[8];

    // ---- prologue: prime 8-deep load pipeline ----
    LOADROW(0, 0)  LOADROW(1, 1)  LOADROW(2, 2)  LOADROW(3, 3)
    LOADROW(4, 4)  LOADROW(5, 5)  LOADROW(6, 6)  LOADROW(7, 7)

    // peel gray rows 0,1 (consume-then-refill keeps 8-deep steady state)
    GRAY8(0, 0, 0)  LOADROW(8, 0)
    GRAY8(1, 1, 1)  LOADROW(9, 1)

    float mA, mB, mC, mD;                        // quad mags (masked)
    int   oA, oB, oC, oD;                        // quad NMS offsets (masked)
    float sxA, syA, sxB, syB, sxC, syC, sxD, syD;
    int   cA, cB, cC, cD;                        // eps-band conditions
    float mc_p;  int off_p;                      // carry: top row of prev quad

    // ================= quad 0: mag rows 2..5, NMS rows 3,4 =================
    GRAY8(2, 2, 2)  LOADROW(10, 2)
    GRAY8(3, 3, 3)  LOADROW(11, 3)
    GRAY8(4, 4, 4)  LOADROW(12, 4)
    GRAY8(5, 5, 5)  LOADROW(13, 5)
    SOBEL(2, mA, oA, sxA, syA, cA)
    SOBEL(3, mB, oB, sxB, syB, cB)
    SOBEL(4, mC, oC, sxC, syC, cC)
    SOBEL(5, mD, oD, sxD, syD, cD)
    if (__builtin_expect(cA | cB | cC | cD, 0)) {
        FIXROW(2, oA, sxA, syA, cA)
        FIXROW(3, oB, sxB, syB, cB)
        FIXROW(4, oC, sxC, syC, cC)
        FIXROW(5, oD, sxD, syD, cD)
    }
    NMSROW(3, mB, oB)
    NMSROW(4, mC, oC)
    mc_p = mD;  off_p = oD;                      // carry mag/off of row 5

    // ================= quad 1: mag rows 6..9, NMS rows 5..8 ================
    GRAY8(6, 6, 6)  LOADROW(14, 6)
    GRAY8(7, 7, 7)  LOADROW(15, 7)
    GRAY8(8, 0, 0)
    GRAY8(9, 1, 1)
    SOBEL(6, mA, oA, sxA, syA, cA)
    SOBEL(7, mB, oB, sxB, syB, cB)
    SOBEL(8, mC, oC, sxC, syC, cC)
    SOBEL(9, mD, oD, sxD, syD, cD)
    if (__builtin_expect(cA | cB | cC | cD, 0)) {
        FIXROW(6, oA, sxA, syA, cA)
        FIXROW(7, oB, sxB, syB, cB)
        FIXROW(8, oC, sxC, syC, cC)
        FIXROW(9, oD, sxD, syD, cD)
    }
    NMSROW(5, mc_p, off_p)
    NMSROW(6, mA, oA)
    NMSROW(7, mB, oB)
    NMSROW(8, mC, oC)
    mc_p = mD;  off_p = oD;                      // carry row 9

    // ================ quad 2: mag rows 10..13, NMS rows 9..12 ==============
    GRAY8(10, 2, 2)
    GRAY8(11, 3, 3)
    GRAY8(12, 4, 4)
    GRAY8(13, 5, 5)
    SOBEL(10, mA, oA, sxA, syA, cA)
    SOBEL(11, mB, oB, sxB, syB, cB)
    SOBEL(12, mC, oC, sxC, syC, cC)
    SOBEL(13, mD, oD, sxD, syD, cD)
    if (__builtin_expect(cA | cB | cC | cD, 0)) {
        FIXROW(10, oA, sxA, syA, cA)
        FIXROW(11, oB, sxB, syB, cB)
        FIXROW(12, oC, sxC, syC, cC)
        FIXROW(13, oD, sxD, syD, cD)
    }
    NMSROW(9,  mc_p, off_p)
    NMSROW(10, mA, oA)
    NMSROW(11, mB, oB)
    NMSROW(12, mC, oC)
    mc_p = mD;  off_p = oD;                      // carry row 13

    // ================ quad 3: mag rows 14,15, NMS rows 13,14 ===============
    GRAY8(14, 6, 6)
    GRAY8(15, 7, 7)
    SOBEL(14, mA, oA, sxA, syA, cA)
    SOBEL(15, mB, oB, sxB, syB, cB)
    if (__builtin_expect(cA | cB, 0)) {
        FIXROW(14, oA, sxA, syA, cA)
        FIXROW(15, oB, sxB, syB, cB)
    }
    NMSROW(13, mc_p, off_p)
    NMSROW(14, mA, oA)
}

extern "C" void kernel_launch(void* const* d_in, const int* in_sizes, int n_in,
                              void* d_out, int out_size, void* d_ws, size_t ws_size,
                              hipStream_t stream) {
    const float* img = (const float*)d_in[0];
    float* out = (float*)d_out;
    // 64 x-strips (60 cols each, 64*60 = 3840 exact) x 180 y-strips (12 rows, exact)
    dim3 grid(64 / 4, IMG_H / R);                // (16, 180) = 2880 blocks, 4 waves each
    dim3 block(64, 4);
    canny_like_kernel<<<grid, block, 0, stream>>>(img, out);
}